// Round 4
// baseline (473.725 us; speedup 1.0000x reference)
//
#include <hip/hip_runtime.h>
#include <hip/hip_bf16.h>

// GCN 4-layer, linear network => collapse to:
// out = A^4 x0 * c4 + A^3 1 * c3 + A^2 1 * c2 + A 1 * c1 + b4,
// A = D^-1/2 (Adj+I) D^-1/2. Propagate in scaled space u' = D^-1 (Adj+I) u,
// epilogue multiplies sqrt(deg). Channels (x-path, ones-path) packed float2.
// Dtypes (R1-R4 verified): read_length int32, edge_index int32, W/b fp32, out fp32.
//
// R11: (a) gather_csr loads epart2 via __builtin_nontemporal_load. R10
// counters: FETCH 81.7MB vs ~38MB logical -> ~45MB is vin line re-fetch.
// vin (4MB) fits an XCD L2 exactly, but the 32MB epart2 stream (zero reuse)
// evicts it every sweep. nt-hint keeps the stream out of L2 -> vin stays
// resident, random loads hit L2 (~200cy) not HBM (~900cy).
// (b) bucket_tot / scan_table were 512-thread (8-wave!) kernels doing 512
// strided global accesses each = ~10-30us of near-idle GPU per kernel.
// Now: bucket_tot = 512 blocks x 256 + LDS reduce; scan_table = 512 blocks
// x 1 wave, shfl prefix scan (lane owns 8 j-slots).

#define BLK  256
#define SBLK 1024         // scatter/count block
#define NB   512          // buckets
#define BSH  10           // bucket = dst >> 10  (1024 nodes / bucket)
#define PB   512          // partition blocks
#define BUFCAP 15872      // scatter LDS sort buffer (chunk = ceil(8M/512) = 15625)
#define BUF2 18176        // csr_build LDS buffer (bucket mean 16384, sd ~128)

// If rl were int64 (values in [0,20000)), every odd int32 word is 0.
__global__ void probe_i64(const int* __restrict__ rl32, int* __restrict__ flag) {
    int acc = 0;
    for (int k = threadIdx.x; k < 1024; k += blockDim.x)
        acc |= rl32[2 * k + 1];
    if (acc != 0) atomicOr(flag, 1);   // 1 => int32 layout
}

__global__ __launch_bounds__(SBLK)
void bucket_count(const int* __restrict__ dst, int* __restrict__ table, int E) {
    __shared__ int h[NB];
    int j = blockIdx.x, t = threadIdx.x;
    for (int b = t; b < NB; b += SBLK) h[b] = 0;
    __syncthreads();
    int chunk = (E + PB - 1) / PB;
    int beg = j * chunk, end = min(beg + chunk, E);
    for (int e = beg + t; e < end; e += SBLK)
        atomicAdd(&h[((unsigned)dst[e]) >> BSH], 1);
    __syncthreads();
    for (int b = t; b < NB; b += SBLK) table[j * NB + b] = h[b];   // coalesced
}

// R11: one block per bucket, LDS tree reduce (was 512 threads total).
__global__ void bucket_tot(const int* __restrict__ table, int* __restrict__ tot) {
    __shared__ int sm[BLK];
    int b = blockIdx.x, t = threadIdx.x;
    int s = 0;
    for (int j = t; j < PB; j += BLK) s += table[j * NB + b];
    sm[t] = s; __syncthreads();
    for (int off = BLK / 2; off > 0; off >>= 1) {
        if (t < off) sm[t] += sm[t + off];
        __syncthreads();
    }
    if (t == 0) tot[b] = sm[0];
}

__global__ void scan_base(const int* __restrict__ tot, int* __restrict__ base) {
    __shared__ int sm[BLK];
    int t = threadIdx.x;
    int loc[NB / BLK]; int s = 0;
#pragma unroll
    for (int k = 0; k < NB / BLK; ++k) { loc[k] = tot[t * (NB / BLK) + k]; s += loc[k]; }
    sm[t] = s; __syncthreads();
    int v = s;
    for (int off = 1; off < BLK; off <<= 1) {
        int add = (t >= off) ? sm[t - off] : 0;
        __syncthreads(); sm[t] += add; __syncthreads();
    }
    int run = sm[t] - v;   // exclusive across threads
#pragma unroll
    for (int k = 0; k < NB / BLK; ++k) { base[t * (NB / BLK) + k] = run; run += loc[k]; }
    if (t == BLK - 1) base[NB] = run;   // == E
}

// R11: one block (1 wave) per bucket; lane owns 8 consecutive j-slots,
// shfl exclusive scan across lanes. table[j][b] := base[b]+sum_{j'<j}.
__global__ __launch_bounds__(64)
void scan_table(int* __restrict__ table, const int* __restrict__ base) {
    int b = blockIdx.x, lane = threadIdx.x;
    int v[PB / 64]; int s = 0;
#pragma unroll
    for (int k = 0; k < PB / 64; ++k) {
        v[k] = table[(lane * (PB / 64) + k) * NB + b];
        s += v[k];
    }
    int run = s;
    for (int off = 1; off < 64; off <<= 1) {
        int u = __shfl_up(run, off);
        if (lane >= off) run += u;
    }
    run -= s;                 // exclusive over lanes
    run += base[b];
#pragma unroll
    for (int k = 0; k < PB / 64; ++k) {
        int t = v[k];
        table[(lane * (PB / 64) + k) * NB + b] = run;
        run += t;
    }
}

// R9: block-local counting sort; emit bucket runs with dense coalesced stores.
__global__ __launch_bounds__(SBLK)
void scatter(const int* __restrict__ src, const int* __restrict__ dst,
             const int* __restrict__ table, unsigned* __restrict__ epart, int E) {
    __shared__ unsigned buf[BUFCAP];     // 62 KB
    __shared__ int h[NB];                // per-subchunk counts
    __shared__ int cur[NB];              // scan / fill cursor
    __shared__ int rbase[NB];            // running global base per bucket
    int j = blockIdx.x, t = threadIdx.x;
    for (int b = t; b < NB; b += SBLK) rbase[b] = table[j * NB + b];
    int chunk = (E + PB - 1) / PB;
    int beg = j * chunk, end = min(beg + chunk, E);
    for (int s = beg; s < end; s += BUFCAP) {
        int se = min(s + BUFCAP, end);
        for (int b = t; b < NB; b += SBLK) h[b] = 0;
        __syncthreads();
        for (int e = s + t; e < se; e += SBLK)
            atomicAdd(&h[((unsigned)dst[e]) >> BSH], 1);
        __syncthreads();
        // inclusive scan of h into cur (NB entries, Hillis-Steele)
        if (t < NB) cur[t] = h[t];
        __syncthreads();
        for (int off = 1; off < NB; off <<= 1) {
            int add = 0;
            if (t < NB && t >= off) add = cur[t - off];
            __syncthreads();
            if (t < NB) cur[t] += add;
            __syncthreads();
        }
        if (t < NB) cur[t] -= h[t];      // exclusive start
        __syncthreads();
        // fill LDS buffer sorted by bucket
        for (int e = s + t; e < se; e += SBLK) {
            unsigned d = (unsigned)dst[e];
            int b = d >> BSH;
            int slot = atomicAdd(&cur[b], 1);
            buf[slot] = ((d & 1023u) << 19) | (unsigned)src[e];
        }
        __syncthreads();
        // copy out: wave w handles buckets w, w+16, ... (runs are contiguous)
        int w = t >> 6, lane = t & 63;
        for (int b = w; b < NB; b += (SBLK >> 6)) {
            int n = h[b];
            int lo = cur[b] - n;         // cur is back to inclusive after fill
            int gb = rbase[b];
            for (int k = lane; k < n; k += 64)
                epart[gb + k] = buf[lo + k];
        }
        __syncthreads();
        if (t < NB) rbase[t] += h[t];
        __syncthreads();
    }
}

// one-time: within each bucket, order edges by local dst node (CSR) and emit
// rowp[node]. 1024 nodes/bucket, one node per thread. R10: scatter lands in
// LDS, then one dense coalesced sweep to global (kills write amplification).
__global__ __launch_bounds__(1024)
void csr_build(const unsigned* __restrict__ epart, const int* __restrict__ base,
               unsigned* __restrict__ epart2, int* __restrict__ rowp) {
    __shared__ unsigned buf[BUF2];     // 71 KB
    __shared__ int sc[1024];           // counts -> inclusive scan (in place)
    __shared__ int cur[1024];          // fill cursors (local slots)
    int b = blockIdx.x, t = threadIdx.x;
    int beg = base[b], end = base[b + 1];
    int n = end - beg;
    sc[t] = 0;
    __syncthreads();
    for (int e = beg + t; e < end; e += 1024)
        atomicAdd(&sc[epart[e] >> 19], 1);
    __syncthreads();
    int v = sc[t];
    for (int off = 1; off < 1024; off <<= 1) {
        int add = (t >= off) ? sc[t - off] : 0;
        __syncthreads(); sc[t] += add; __syncthreads();
    }
    int start = sc[t] - v;             // exclusive, bucket-local slot
    rowp[b * 1024 + t] = beg + start;
    if (t == 1023) rowp[b * 1024 + 1024] = end;   // dup of next block's t=0 (same value)
    cur[t] = start;
    __syncthreads();
    if (n <= BUF2) {
        // sort into LDS
        for (int e = beg + t; e < end; e += 1024) {
            unsigned p = epart[e];
            int slot = atomicAdd(&cur[p >> 19], 1);
            buf[slot] = p & 0x7FFFFu;   // just src (19 bits)
        }
        __syncthreads();
        // dense coalesced write-out: lines written once, full
        for (int k = t; k < n; k += 1024)
            epart2[beg + k] = buf[k];
    } else {
        // overflow fallback (statistically unreachable): global scatter
        for (int e = beg + t; e < end; e += 1024) {
            unsigned p = epart[e];
            int slot = atomicAdd(&cur[p >> 19], 1);
            epart2[beg + slot] = p & 0x7FFFFu;
        }
    }
}

// node init; in-degree free from rowp
__global__ void init_nodes(const int* __restrict__ rl, const int* __restrict__ rowp,
                           float* __restrict__ dinv, float2* __restrict__ v0,
                           const int* __restrict__ flag, int N) {
    int i = blockIdx.x * blockDim.x + threadIdx.x;
    if (i < N) {
        int v = (*flag) ? rl[i] : rl[2 * i];
        float d = (float)(rowp[i + 1] - rowp[i]) + 1.0f;   // + self-loop
        dinv[i] = 1.0f / d;
        float rs = rsqrtf(d);
        float2 u; u.x = rs * ((float)v * (1.0f / 20000.0f)); u.y = rs;
        v0[i] = u;
    }
}

__global__ void coeffs(const float* __restrict__ W1, const float* __restrict__ b1,
                       const float* __restrict__ W2, const float* __restrict__ b2,
                       const float* __restrict__ W3, const float* __restrict__ b3,
                       const float* __restrict__ W4, const float* __restrict__ b4,
                       float* __restrict__ c) {
    __shared__ float p3[16], q3[16], r3[16];
    int t = threadIdx.x;
    if (t == 0) {
        float p2[8], q2[8];
        for (int j = 0; j < 8; ++j) {
            float s1 = 0.f, s2 = 0.f;
            for (int k = 0; k < 4; ++k) {
                float w = W2[k * 8 + j];
                s1 += W1[k] * w;
                s2 += b1[k] * w;
            }
            p2[j] = s1; q2[j] = s2;
        }
        for (int m = 0; m < 16; ++m) {
            float s1 = 0.f, s2 = 0.f, s3 = 0.f;
            for (int j = 0; j < 8; ++j) {
                float w = W3[j * 16 + m];
                s1 += p2[j] * w; s2 += q2[j] * w;
                s3 += b2[j] * w;
            }
            p3[m] = s1; q3[m] = s2; r3[m] = s3;
        }
    }
    __syncthreads();
    if (t < 32) {
        float c4 = 0.f, c3 = 0.f, c2 = 0.f, c1 = 0.f;
        for (int k = 0; k < 16; ++k) {
            float w = W4[k * 32 + t];
            c4 += p3[k] * w; c3 += q3[k] * w; c2 += r3[k] * w;
            c1 += b3[k] * w;
        }
        c[t] = c4; c[32 + t] = c3; c[64 + t] = c2; c[96 + t] = c1;
    }
}

// one sweep: 8 lanes/node, register accumulate, x2 paired loads in flight.
// R11: epart2 stream read nontemporal (protect vin residency in L2).
__global__ void gather_csr(const unsigned* __restrict__ epart2, const int* __restrict__ rowp,
                           const float2* __restrict__ vin, float2* __restrict__ vout,
                           const float* __restrict__ dinv, float* __restrict__ zsave, int N) {
    int t = blockIdx.x * blockDim.x + threadIdx.x;
    int i = t >> 3, l = t & 7;
    if (i >= N) return;
    int beg = rowp[i], end = rowp[i + 1];
    float a = 0.f, b = 0.f;
    int j = beg + l;
    for (; j + 8 < end; j += 16) {         // two independent loads in flight
        int s0 = (int)__builtin_nontemporal_load(&epart2[j]);
        int s1 = (int)__builtin_nontemporal_load(&epart2[j + 8]);
        float2 u0 = vin[s0];
        float2 u1 = vin[s1];
        a += u0.x + u1.x; b += u0.y + u1.y;
    }
    if (j < end) {
        int s = (int)__builtin_nontemporal_load(&epart2[j]);
        float2 u = vin[s];
        a += u.x; b += u.y;
    }
    a += __shfl_xor(a, 1); b += __shfl_xor(b, 1);
    a += __shfl_xor(a, 2); b += __shfl_xor(b, 2);
    a += __shfl_xor(a, 4); b += __shfl_xor(b, 4);
    if (l == 0) {
        float2 self = vin[i];
        float di = dinv[i];
        float2 o; o.x = (a + self.x) * di; o.y = (b + self.y) * di;
        vout[i] = o;
        if (zsave) zsave[i] = o.y;
    }
}

__global__ void write_out(const float2* __restrict__ v0, const float* __restrict__ z1,
                          const float* __restrict__ z2, const float* __restrict__ z3,
                          const float* __restrict__ dinv, const float* __restrict__ c,
                          const float* __restrict__ b4,
                          float* __restrict__ out, int N) {
    int t = blockIdx.x * blockDim.x + threadIdx.x;
    int i = t >> 5, f = t & 31;
    if (i < N) {
        float sq = rsqrtf(dinv[i]);  // = sqrt(deg)
        float v = sq * (v0[i].x * c[f] + z3[i] * c[32 + f] + z2[i] * c[64 + f]
                        + z1[i] * c[96 + f])
                  + b4[f];
        out[(size_t)i * 32 + f] = v;
    }
}

extern "C" void kernel_launch(void* const* d_in, const int* in_sizes, int n_in,
                              void* d_out, int out_size, void* d_ws, size_t ws_size,
                              hipStream_t stream) {
    const int N = in_sizes[0];
    const int E = in_sizes[1] / 2;
    const int* rl  = (const int*)d_in[0];
    const int* src = (const int*)d_in[1];
    const int* dst = src + E;
    const float* W1 = (const float*)d_in[2];
    const float* b1 = (const float*)d_in[3];
    const float* W2 = (const float*)d_in[4];
    const float* b2 = (const float*)d_in[5];
    const float* W3 = (const float*)d_in[6];
    const float* b3 = (const float*)d_in[7];
    const float* W4 = (const float*)d_in[8];
    const float* b4 = (const float*)d_in[9];

    const int gbNode = (N + 1023) / 1024;     // buckets containing nodes (489)
    const int rowpN  = gbNode * 1024 + 1;     // rowp entries

    // workspace (~19.1 MB)
    float*  dinv = (float*)d_ws;              // N
    float2* v0   = (float2*)(dinv + N);       // 2N floats
    float2* v1   = v0 + N;                    // 2N floats
    float*  z1   = (float*)(v1 + N);          // N
    float*  z2   = z1 + N;                    // N
    float*  z3   = z2 + N;                    // N
    int*    table = (int*)(z3 + N);           // PB*NB ints (1 MB)
    int*    rowp  = table + PB * NB;          // rowpN ints (~2 MB)
    int*    btot  = rowp + rowpN + 3;         // NB
    int*    bbase = btot + NB;                // NB+1
    float*  c     = (float*)(bbase + NB + 1); // 128
    int*    flag  = (int*)(c + 128);          // 1

    // packed edge arrays live in d_out (scratch until write_out)
    unsigned* epart  = (unsigned*)d_out;      // E uint32 (first 32 MB)
    unsigned* epart2 = epart + E;             // E uint32 (second 32 MB)

    hipMemsetAsync(flag, 0, sizeof(int), stream);
    probe_i64<<<1, BLK, 0, stream>>>(rl, flag);

    // radix partition by dst bucket — zero global atomics
    bucket_count<<<PB, SBLK, 0, stream>>>(dst, table, E);
    bucket_tot<<<NB, BLK, 0, stream>>>(table, btot);
    scan_base<<<1, BLK, 0, stream>>>(btot, bbase);
    scan_table<<<NB, 64, 0, stream>>>(table, bbase);
    scatter<<<PB, SBLK, 0, stream>>>(src, dst, table, epart, E);

    // within-bucket CSR
    csr_build<<<gbNode, 1024, 0, stream>>>(epart, bbase, epart2, rowp);

    init_nodes<<<(N + BLK - 1) / BLK, BLK, 0, stream>>>(rl, rowp, dinv, v0, flag, N);
    coeffs<<<1, 64, 0, stream>>>(W1, b1, W2, b2, W3, b3, W4, b4, c);

    // 4 propagation sweeps, ping-pong v0<->v1 (8 lanes/node)
    const int gbG = (8 * N + BLK - 1) / BLK;
    gather_csr<<<gbG, BLK, 0, stream>>>(epart2, rowp, v0, v1, dinv, z1, N);
    gather_csr<<<gbG, BLK, 0, stream>>>(epart2, rowp, v1, v0, dinv, z2, N);
    gather_csr<<<gbG, BLK, 0, stream>>>(epart2, rowp, v0, v1, dinv, z3, N);
    gather_csr<<<gbG, BLK, 0, stream>>>(epart2, rowp, v1, v0, dinv, (float*)nullptr, N);

    write_out<<<(N * 32 + BLK - 1) / BLK, BLK, 0, stream>>>(
        v0, z1, z2, z3, dinv, c, b4, (float*)d_out, N);
}

// Round 5
// 419.157 us; speedup vs baseline: 1.1302x; 1.1302x over previous
//
#include <hip/hip_runtime.h>
#include <hip/hip_bf16.h>

// GCN 4-layer, linear network => collapse to:
// out = A^4 x0 * c4 + A^3 1 * c3 + A^2 1 * c2 + A 1 * c1 + b4,
// A = D^-1/2 (Adj+I) D^-1/2. Propagate in scaled space u' = D^-1 (Adj+I) u,
// epilogue multiplies sqrt(deg). Channels (x-path, ones-path) packed float2.
// Dtypes (R1-R4 verified): read_length int32, edge_index int32, W/b fp32, out fp32.
//
// R12: (a) REVERT R11's nontemporal epart2 loads: FETCH dropped 82->67MB but
// dur rose 52->62us/sweep — epart2 has real cross-wave L2 line reuse, and nt
// turned those hits into HBM misses on the dependent epart2->vin chain.
// (b) Fuse write_out into sweep 4 (gather_out): after the xor-butterfly all
// 8 lanes hold the sum; each lane writes a float4 (128B/node contiguous).
// Only legal when epart2 lives in workspace (out aliases d_out) — runtime
// branch on ws_size, fallback = old split path. (c) 3 fewer dispatches:
// probe self-writes flag (no memset); scan_base folded into scan_table /
// csr_build (in-wave prefix over btot); coeffs folded into init_nodes.

#define BLK  256
#define SBLK 1024         // scatter/count block
#define NB   512          // buckets
#define BSH  10           // bucket = dst >> 10  (1024 nodes / bucket)
#define PB   512          // partition blocks
#define BUFCAP 15872      // scatter LDS sort buffer (chunk = ceil(8M/512) = 15625)
#define BUF2 18176        // csr_build LDS buffer (bucket mean 16384, sd ~128)

// If rl were int64 (values in [0,20000)), every odd int32 word is 0.
// R12: block-reduce, thread0 writes flag (no separate memset dispatch).
__global__ void probe_i64(const int* __restrict__ rl32, int* __restrict__ flag) {
    __shared__ int sm[BLK];
    int t = threadIdx.x;
    int acc = 0;
    for (int k = t; k < 1024; k += blockDim.x)
        acc |= rl32[2 * k + 1];
    sm[t] = acc; __syncthreads();
    for (int off = BLK / 2; off > 0; off >>= 1) {
        if (t < off) sm[t] |= sm[t + off];
        __syncthreads();
    }
    if (t == 0) *flag = (sm[0] != 0) ? 1 : 0;   // 1 => int32 layout
}

__global__ __launch_bounds__(SBLK)
void bucket_count(const int* __restrict__ dst, int* __restrict__ table, int E) {
    __shared__ int h[NB];
    int j = blockIdx.x, t = threadIdx.x;
    for (int b = t; b < NB; b += SBLK) h[b] = 0;
    __syncthreads();
    int chunk = (E + PB - 1) / PB;
    int beg = j * chunk, end = min(beg + chunk, E);
    for (int e = beg + t; e < end; e += SBLK)
        atomicAdd(&h[((unsigned)dst[e]) >> BSH], 1);
    __syncthreads();
    for (int b = t; b < NB; b += SBLK) table[j * NB + b] = h[b];   // coalesced
}

// one block per bucket, LDS tree reduce
__global__ void bucket_tot(const int* __restrict__ table, int* __restrict__ tot) {
    __shared__ int sm[BLK];
    int b = blockIdx.x, t = threadIdx.x;
    int s = 0;
    for (int j = t; j < PB; j += BLK) s += table[j * NB + b];
    sm[t] = s; __syncthreads();
    for (int off = BLK / 2; off > 0; off >>= 1) {
        if (t < off) sm[t] += sm[t + off];
        __syncthreads();
    }
    if (t == 0) tot[b] = sm[0];
}

// one block (1 wave) per bucket; lane owns 8 consecutive j-slots, shfl
// prefix scan across lanes. R12: base[b] computed in-wave from btot
// (scan_base kernel dropped). table[j][b] := base[b]+sum_{j'<j}.
__global__ __launch_bounds__(64)
void scan_table(int* __restrict__ table, const int* __restrict__ btot) {
    int b = blockIdx.x, lane = threadIdx.x;
    // base[b] = sum_{k<b} btot[k]
    int pre = 0;
    for (int k = lane; k < NB; k += 64)
        if (k < b) pre += btot[k];
    for (int off = 1; off < 64; off <<= 1) pre += __shfl_xor(pre, off);
    int v[PB / 64]; int s = 0;
#pragma unroll
    for (int k = 0; k < PB / 64; ++k) {
        v[k] = table[(lane * (PB / 64) + k) * NB + b];
        s += v[k];
    }
    int run = s;
    for (int off = 1; off < 64; off <<= 1) {
        int u = __shfl_up(run, off);
        if (lane >= off) run += u;
    }
    run -= s;                 // exclusive over lanes
    run += pre;
#pragma unroll
    for (int k = 0; k < PB / 64; ++k) {
        int t = v[k];
        table[(lane * (PB / 64) + k) * NB + b] = run;
        run += t;
    }
}

// R9: block-local counting sort; emit bucket runs with dense coalesced stores.
__global__ __launch_bounds__(SBLK)
void scatter(const int* __restrict__ src, const int* __restrict__ dst,
             const int* __restrict__ table, unsigned* __restrict__ epart, int E) {
    __shared__ unsigned buf[BUFCAP];     // 62 KB
    __shared__ int h[NB];                // per-subchunk counts
    __shared__ int cur[NB];              // scan / fill cursor
    __shared__ int rbase[NB];            // running global base per bucket
    int j = blockIdx.x, t = threadIdx.x;
    for (int b = t; b < NB; b += SBLK) rbase[b] = table[j * NB + b];
    int chunk = (E + PB - 1) / PB;
    int beg = j * chunk, end = min(beg + chunk, E);
    for (int s = beg; s < end; s += BUFCAP) {
        int se = min(s + BUFCAP, end);
        for (int b = t; b < NB; b += SBLK) h[b] = 0;
        __syncthreads();
        for (int e = s + t; e < se; e += SBLK)
            atomicAdd(&h[((unsigned)dst[e]) >> BSH], 1);
        __syncthreads();
        // inclusive scan of h into cur (NB entries, Hillis-Steele)
        if (t < NB) cur[t] = h[t];
        __syncthreads();
        for (int off = 1; off < NB; off <<= 1) {
            int add = 0;
            if (t < NB && t >= off) add = cur[t - off];
            __syncthreads();
            if (t < NB) cur[t] += add;
            __syncthreads();
        }
        if (t < NB) cur[t] -= h[t];      // exclusive start
        __syncthreads();
        // fill LDS buffer sorted by bucket
        for (int e = s + t; e < se; e += SBLK) {
            unsigned d = (unsigned)dst[e];
            int b = d >> BSH;
            int slot = atomicAdd(&cur[b], 1);
            buf[slot] = ((d & 1023u) << 19) | (unsigned)src[e];
        }
        __syncthreads();
        // copy out: wave w handles buckets w, w+16, ... (runs are contiguous)
        int w = t >> 6, lane = t & 63;
        for (int b = w; b < NB; b += (SBLK >> 6)) {
            int n = h[b];
            int lo = cur[b] - n;         // cur is back to inclusive after fill
            int gb = rbase[b];
            for (int k = lane; k < n; k += 64)
                epart[gb + k] = buf[lo + k];
        }
        __syncthreads();
        if (t < NB) rbase[t] += h[t];
        __syncthreads();
    }
}

// one-time: within each bucket, order edges by local dst node (CSR) and emit
// rowp[node]. 1024 nodes/bucket, one node per thread. Scatter lands in LDS,
// then one dense coalesced sweep to global. R12: beg/end from in-wave prefix
// over btot (bbase array dropped).
__global__ __launch_bounds__(1024)
void csr_build(const unsigned* __restrict__ epart, const int* __restrict__ btot,
               unsigned* __restrict__ epart2, int* __restrict__ rowp) {
    __shared__ unsigned buf[BUF2];     // 71 KB
    __shared__ int sc[1024];           // counts -> inclusive scan (in place)
    __shared__ int cur[1024];          // fill cursors (local slots)
    __shared__ int s_beg, s_end;
    int b = blockIdx.x, t = threadIdx.x;
    if (t < 64) {
        int pre = 0, tot = 0;
        for (int k = t; k < NB; k += 64) {
            int v = btot[k];
            if (k < b) pre += v;
            if (k == b) tot = v;
        }
        for (int off = 1; off < 64; off <<= 1) {
            pre += __shfl_xor(pre, off);
            tot += __shfl_xor(tot, off);
        }
        if (t == 0) { s_beg = pre; s_end = pre + tot; }
    }
    sc[t] = 0;
    __syncthreads();
    int beg = s_beg, end = s_end;
    int n = end - beg;
    for (int e = beg + t; e < end; e += 1024)
        atomicAdd(&sc[epart[e] >> 19], 1);
    __syncthreads();
    int v = sc[t];
    for (int off = 1; off < 1024; off <<= 1) {
        int add = (t >= off) ? sc[t - off] : 0;
        __syncthreads(); sc[t] += add; __syncthreads();
    }
    int start = sc[t] - v;             // exclusive, bucket-local slot
    rowp[b * 1024 + t] = beg + start;
    if (t == 1023) rowp[b * 1024 + 1024] = end;   // boundary (matches next block's t=0)
    cur[t] = start;
    __syncthreads();
    if (n <= BUF2) {
        // sort into LDS
        for (int e = beg + t; e < end; e += 1024) {
            unsigned p = epart[e];
            int slot = atomicAdd(&cur[p >> 19], 1);
            buf[slot] = p & 0x7FFFFu;   // just src (19 bits)
        }
        __syncthreads();
        // dense coalesced write-out: lines written once, full
        for (int k = t; k < n; k += 1024)
            epart2[beg + k] = buf[k];
    } else {
        // overflow fallback (statistically unreachable): global scatter
        for (int e = beg + t; e < end; e += 1024) {
            unsigned p = epart[e];
            int slot = atomicAdd(&cur[p >> 19], 1);
            epart2[beg + slot] = p & 0x7FFFFu;
        }
    }
}

// node init; in-degree free from rowp. R12: last block computes coeffs.
__global__ void init_nodes(const int* __restrict__ rl, const int* __restrict__ rowp,
                           float* __restrict__ dinv, float2* __restrict__ v0,
                           const int* __restrict__ flag, int N,
                           const float* __restrict__ W1, const float* __restrict__ b1,
                           const float* __restrict__ W2, const float* __restrict__ b2,
                           const float* __restrict__ W3, const float* __restrict__ b3,
                           const float* __restrict__ W4, const float* __restrict__ b4,
                           float* __restrict__ c) {
    __shared__ float p3[16], q3[16], r3[16];
    int t = threadIdx.x;
    if (blockIdx.x == gridDim.x - 1) {
        // coeffs block
        if (t == 0) {
            float p2[8], q2[8];
            for (int j = 0; j < 8; ++j) {
                float s1 = 0.f, s2 = 0.f;
                for (int k = 0; k < 4; ++k) {
                    float w = W2[k * 8 + j];
                    s1 += W1[k] * w;
                    s2 += b1[k] * w;
                }
                p2[j] = s1; q2[j] = s2;
            }
            for (int m = 0; m < 16; ++m) {
                float s1 = 0.f, s2 = 0.f, s3 = 0.f;
                for (int j = 0; j < 8; ++j) {
                    float w = W3[j * 16 + m];
                    s1 += p2[j] * w; s2 += q2[j] * w;
                    s3 += b2[j] * w;
                }
                p3[m] = s1; q3[m] = s2; r3[m] = s3;
            }
        }
        __syncthreads();
        if (t < 32) {
            float c4 = 0.f, c3 = 0.f, c2 = 0.f, c1 = 0.f;
            for (int k = 0; k < 16; ++k) {
                float w = W4[k * 32 + t];
                c4 += p3[k] * w; c3 += q3[k] * w; c2 += r3[k] * w;
                c1 += b3[k] * w;
            }
            c[t] = c4; c[32 + t] = c3; c[64 + t] = c2; c[96 + t] = c1;
        }
        return;
    }
    int i = blockIdx.x * blockDim.x + t;
    if (i < N) {
        int v = (*flag) ? rl[i] : rl[2 * i];
        float d = (float)(rowp[i + 1] - rowp[i]) + 1.0f;   // + self-loop
        dinv[i] = 1.0f / d;
        float rs = rsqrtf(d);
        float2 u; u.x = rs * ((float)v * (1.0f / 20000.0f)); u.y = rs;
        v0[i] = u;
    }
}

// one sweep: 8 lanes/node, register accumulate, x2 paired loads in flight.
// R12: plain loads (nt reverted).
__global__ void gather_csr(const unsigned* __restrict__ epart2, const int* __restrict__ rowp,
                           const float2* __restrict__ vin, float2* __restrict__ vout,
                           const float* __restrict__ dinv, float* __restrict__ zsave, int N) {
    int t = blockIdx.x * blockDim.x + threadIdx.x;
    int i = t >> 3, l = t & 7;
    if (i >= N) return;
    int beg = rowp[i], end = rowp[i + 1];
    float a = 0.f, b = 0.f;
    int j = beg + l;
    for (; j + 8 < end; j += 16) {         // two independent loads in flight
        int s0 = epart2[j];
        int s1 = epart2[j + 8];
        float2 u0 = vin[s0];
        float2 u1 = vin[s1];
        a += u0.x + u1.x; b += u0.y + u1.y;
    }
    if (j < end) {
        float2 u = vin[epart2[j]];
        a += u.x; b += u.y;
    }
    a += __shfl_xor(a, 1); b += __shfl_xor(b, 1);
    a += __shfl_xor(a, 2); b += __shfl_xor(b, 2);
    a += __shfl_xor(a, 4); b += __shfl_xor(b, 4);
    if (l == 0) {
        float2 self = vin[i];
        float di = dinv[i];
        float2 o; o.x = (a + self.x) * di; o.y = (b + self.y) * di;
        vout[i] = o;
        if (zsave) zsave[i] = o.y;
    }
}

// R12: fused final sweep + epilogue. Only x-channel accumulated (y of sweep
// 4 is unused). All 8 lanes hold the reduced sum after the butterfly; each
// writes a float4 -> 128B contiguous per node. ONLY valid when epart2 is in
// workspace (out aliases d_out).
__global__ void gather_out(const unsigned* __restrict__ epart2, const int* __restrict__ rowp,
                           const float2* __restrict__ vin, const float* __restrict__ dinv,
                           const float* __restrict__ z1, const float* __restrict__ z2,
                           const float* __restrict__ z3, const float* __restrict__ c,
                           const float* __restrict__ b4, float* __restrict__ out, int N) {
    int t = blockIdx.x * blockDim.x + threadIdx.x;
    int i = t >> 3, l = t & 7;
    if (i >= N) return;
    int beg = rowp[i], end = rowp[i + 1];
    float a = 0.f;
    int j = beg + l;
    for (; j + 8 < end; j += 16) {
        int s0 = epart2[j];
        int s1 = epart2[j + 8];
        a += vin[s0].x + vin[s1].x;
    }
    if (j < end) a += vin[epart2[j]].x;
    a += __shfl_xor(a, 1);
    a += __shfl_xor(a, 2);
    a += __shfl_xor(a, 4);
    float di = dinv[i];
    float ox = (a + vin[i].x) * di;      // final A^4 x (scaled space)
    float sq = rsqrtf(di);               // = sqrt(deg)
    float zz1 = z1[i], zz2 = z2[i], zz3 = z3[i];
    float4 cc4 = *(const float4*)&c[l * 4];
    float4 cc3 = *(const float4*)&c[32 + l * 4];
    float4 cc2 = *(const float4*)&c[64 + l * 4];
    float4 cc1 = *(const float4*)&c[96 + l * 4];
    float4 bb  = *(const float4*)&b4[l * 4];
    float4 o4;
    o4.x = sq * (ox * cc4.x + zz3 * cc3.x + zz2 * cc2.x + zz1 * cc1.x) + bb.x;
    o4.y = sq * (ox * cc4.y + zz3 * cc3.y + zz2 * cc2.y + zz1 * cc1.y) + bb.y;
    o4.z = sq * (ox * cc4.z + zz3 * cc3.z + zz2 * cc2.z + zz1 * cc1.z) + bb.z;
    o4.w = sq * (ox * cc4.w + zz3 * cc3.w + zz2 * cc2.w + zz1 * cc1.w) + bb.w;
    *(float4*)&out[(size_t)i * 32 + l * 4] = o4;
}

// fallback epilogue (split path)
__global__ void write_out(const float2* __restrict__ v0, const float* __restrict__ z1,
                          const float* __restrict__ z2, const float* __restrict__ z3,
                          const float* __restrict__ dinv, const float* __restrict__ c,
                          const float* __restrict__ b4,
                          float* __restrict__ out, int N) {
    int t = blockIdx.x * blockDim.x + threadIdx.x;
    int i = t >> 5, f = t & 31;
    if (i < N) {
        float sq = rsqrtf(dinv[i]);  // = sqrt(deg)
        float v = sq * (v0[i].x * c[f] + z3[i] * c[32 + f] + z2[i] * c[64 + f]
                        + z1[i] * c[96 + f])
                  + b4[f];
        out[(size_t)i * 32 + f] = v;
    }
}

extern "C" void kernel_launch(void* const* d_in, const int* in_sizes, int n_in,
                              void* d_out, int out_size, void* d_ws, size_t ws_size,
                              hipStream_t stream) {
    const int N = in_sizes[0];
    const int E = in_sizes[1] / 2;
    const int* rl  = (const int*)d_in[0];
    const int* src = (const int*)d_in[1];
    const int* dst = src + E;
    const float* W1 = (const float*)d_in[2];
    const float* b1 = (const float*)d_in[3];
    const float* W2 = (const float*)d_in[4];
    const float* b2 = (const float*)d_in[5];
    const float* W3 = (const float*)d_in[6];
    const float* b3 = (const float*)d_in[7];
    const float* W4 = (const float*)d_in[8];
    const float* b4 = (const float*)d_in[9];

    const int gbNode = (N + 1023) / 1024;     // buckets containing nodes (489)
    const int rowpN  = gbNode * 1024 + 1;     // rowp entries

    // workspace layout (all chunks 16B-multiples)
    char* w = (char*)d_ws;
    float2* v0   = (float2*)w;                w += (size_t)N * 8;
    float2* v1   = (float2*)w;                w += (size_t)N * 8;
    float*  dinv = (float*)w;                 w += (size_t)N * 4;
    float*  z1   = (float*)w;                 w += (size_t)N * 4;
    float*  z2   = (float*)w;                 w += (size_t)N * 4;
    float*  z3   = (float*)w;                 w += (size_t)N * 4;
    int*    table = (int*)w;                  w += (size_t)PB * NB * 4;
    int*    rowp  = (int*)w;                  w += (size_t)(rowpN + 3) * 4;
    int*    btot  = (int*)w;                  w += NB * 4;
    float*  c     = (float*)w;                w += 128 * 4;
    int*    flag  = (int*)w;                  w += 16;
    // epart2 in workspace if it fits (enables fused gather_out)
    size_t used = (size_t)(w - (char*)d_ws);
    used = (used + 255) & ~(size_t)255;
    bool fits = (used + (size_t)E * 4) <= ws_size;
    unsigned* epart  = (unsigned*)d_out;      // E uint32 (dead after csr_build)
    unsigned* epart2 = fits ? (unsigned*)((char*)d_ws + used) : (epart + E);

    probe_i64<<<1, BLK, 0, stream>>>(rl, flag);

    // radix partition by dst bucket — zero global atomics
    bucket_count<<<PB, SBLK, 0, stream>>>(dst, table, E);
    bucket_tot<<<NB, BLK, 0, stream>>>(table, btot);
    scan_table<<<NB, 64, 0, stream>>>(table, btot);
    scatter<<<PB, SBLK, 0, stream>>>(src, dst, table, epart, E);

    // within-bucket CSR
    csr_build<<<gbNode, 1024, 0, stream>>>(epart, btot, epart2, rowp);

    const int nInit = (N + BLK - 1) / BLK;
    init_nodes<<<nInit + 1, BLK, 0, stream>>>(rl, rowp, dinv, v0, flag, N,
                                              W1, b1, W2, b2, W3, b3, W4, b4, c);

    // 4 propagation sweeps, ping-pong v0<->v1 (8 lanes/node)
    const int gbG = (8 * N + BLK - 1) / BLK;
    gather_csr<<<gbG, BLK, 0, stream>>>(epart2, rowp, v0, v1, dinv, z1, N);
    gather_csr<<<gbG, BLK, 0, stream>>>(epart2, rowp, v1, v0, dinv, z2, N);
    gather_csr<<<gbG, BLK, 0, stream>>>(epart2, rowp, v0, v1, dinv, z3, N);
    if (fits) {
        gather_out<<<gbG, BLK, 0, stream>>>(epart2, rowp, v1, dinv, z1, z2, z3,
                                            c, b4, (float*)d_out, N);
    } else {
        gather_csr<<<gbG, BLK, 0, stream>>>(epart2, rowp, v1, v0, dinv, (float*)nullptr, N);
        write_out<<<(N * 32 + BLK - 1) / BLK, BLK, 0, stream>>>(
            v0, z1, z2, z3, dinv, c, b4, (float*)d_out, N);
    }
}